// Round 3
// baseline (1560.933 us; speedup 1.0000x reference)
//
#include <hip/hip_runtime.h>

#define IN_CH 65
#define HID 64
#define BN 128      // nodes per bucket
#define NB 782      // ceil(100000 / BN)
#define CAP 8192    // pair slots per bucket; deg~Poisson(4096), sd 64 -> 64 sigma
#define EPB 8192    // edges per scatter block

static inline size_t align16(size_t v) { return (v + 15) & ~(size_t)15; }

// ---------------------------------------------------------------------------
// prep_wt: Wt[c][j], c in [0,65), j in [0,128): j<64 -> W_rel[j][c],
// j>=64 -> W_root[j-64][c].
// ---------------------------------------------------------------------------
__global__ __launch_bounds__(128) void prep_wt(const float* __restrict__ W_rel,
                                               const float* __restrict__ W_root,
                                               float* __restrict__ Wt) {
    const int j = threadIdx.x;
    const float* W = (j < HID) ? (W_rel + j * IN_CH) : (W_root + (j - HID) * IN_CH);
    for (int c = 0; c < IN_CH; ++c)
        Wt[c * 128 + j] = W[c];
}

// ---------------------------------------------------------------------------
// k1: [64 x 65] @ [65 x 128] per block. cols<64 -> y, cols>=64 -> out(+bias).
// (unchanged from R2 — known good, ~sub-100us)
// ---------------------------------------------------------------------------
__global__ __launch_bounds__(256) void k1(const float* __restrict__ x,
                                          const float* __restrict__ Wt,
                                          const float* __restrict__ b_rel,
                                          float* __restrict__ y,
                                          float* __restrict__ out,
                                          int nNodes) {
    __shared__ float xs[64 * IN_CH];
    __shared__ float ws[IN_CH * 128];
    const int tid = threadIdx.x;
    const int tx = tid & 15;
    const int ty = tid >> 4;
    const long nodeBase = (long)blockIdx.x * 64;
    const int nValid = min(64, nNodes - (int)nodeBase);
    const int nx = nValid * IN_CH;

    const float* xsrc = x + nodeBase * IN_CH;
    for (int i = tid; i < 64 * IN_CH; i += 256) xs[i] = (i < nx) ? xsrc[i] : 0.f;
    for (int i = tid; i < IN_CH * 128; i += 256) ws[i] = Wt[i];
    __syncthreads();

    float acc[4][8];
#pragma unroll
    for (int i = 0; i < 4; ++i)
#pragma unroll
        for (int j = 0; j < 8; ++j) acc[i][j] = 0.f;

    const int r0 = ty * 4;
    const int c0 = tx * 8;
    for (int k = 0; k < IN_CH; ++k) {
        float aa[4] = {xs[(r0 + 0) * IN_CH + k], xs[(r0 + 1) * IN_CH + k],
                       xs[(r0 + 2) * IN_CH + k], xs[(r0 + 3) * IN_CH + k]};
        float4 b0 = *(const float4*)&ws[k * 128 + c0];
        float4 b1 = *(const float4*)&ws[k * 128 + c0 + 4];
        float bb[8] = {b0.x, b0.y, b0.z, b0.w, b1.x, b1.y, b1.z, b1.w};
#pragma unroll
        for (int i = 0; i < 4; ++i)
#pragma unroll
            for (int j = 0; j < 8; ++j) acc[i][j] += aa[i] * bb[j];
    }

    if (c0 >= HID) {
        const int h0 = c0 - HID;
        float4 bb0 = *(const float4*)&b_rel[h0];
        float4 bb1 = *(const float4*)&b_rel[h0 + 4];
        float bv[8] = {bb0.x, bb0.y, bb0.z, bb0.w, bb1.x, bb1.y, bb1.z, bb1.w};
#pragma unroll
        for (int i = 0; i < 4; ++i)
#pragma unroll
            for (int j = 0; j < 8; ++j) acc[i][j] += bv[j];
    }

#pragma unroll
    for (int i = 0; i < 4; ++i) {
        const long node = nodeBase + r0 + i;
        if (node >= nNodes) break;
        float* dst = (c0 < HID) ? (y + node * HID + c0)
                                : (out + node * HID + (c0 - HID));
        *(float4*)(dst + 0) = make_float4(acc[i][0], acc[i][1], acc[i][2], acc[i][3]);
        *(float4*)(dst + 4) = make_float4(acc[i][4], acc[i][5], acc[i][6], acc[i][7]);
    }
}

// ---------------------------------------------------------------------------
// scatterB: coarse bucket partition with per-block contiguous runs.
// Block handles EPB edges: LDS hist -> one global atomicAdd per touched
// bucket reserves a contiguous run -> writes land in ~10-slot runs owned by
// this CU (write amp ~7.7x -> ~1.5x).
// pair = (src | dstLocal<<17, bits(w));  src<2^17, dstLocal<128.
// ---------------------------------------------------------------------------
__global__ __launch_bounds__(256) void scatterB(const int* __restrict__ ei,
                                                const float* __restrict__ ew,
                                                int* __restrict__ cnt,
                                                int2* __restrict__ pairs, int E) {
    __shared__ int lhist[NB];
    __shared__ int lbase[NB];
    const int tid = threadIdx.x;
    const long e0 = (long)blockIdx.x * EPB;
    const int n = (int)min((long)EPB, (long)E - e0);

    for (int i = tid; i < NB; i += 256) lhist[i] = 0;
    __syncthreads();

    int dstv[EPB / 256];  // cache dst for phase 3
#pragma unroll 1
    for (int i = tid, k = 0; i < n; i += 256, ++k) {
        const int dst = ei[(long)E + e0 + i];
        dstv[k] = dst;
        atomicAdd(&lhist[dst >> 7], 1);
    }
    __syncthreads();

    for (int i = tid; i < NB; i += 256) {
        const int c = lhist[i];
        lbase[i] = c ? atomicAdd(&cnt[i], c) : 0;
        lhist[i] = 0;  // reuse as local cursor
    }
    __syncthreads();

#pragma unroll 1
    for (int i = tid, k = 0; i < n; i += 256, ++k) {
        const int dst = dstv[k];
        const int src = ei[e0 + i];
        const float w = ew[e0 + i];
        const int b = dst >> 7;
        const int p = lbase[b] + atomicAdd(&lhist[b], 1);
        pairs[(size_t)b * CAP + p] =
            make_int2(src | ((dst & (BN - 1)) << 17), __float_as_int(w));
    }
}

// ---------------------------------------------------------------------------
// aggregateB: one block per bucket. 32 KB LDS acc[128 nodes][64 ch].
// Per edge: wave-uniform pair load, 256B coalesced gather of y[src],
// ds_add_f32 into acc (lane->bank 2:1, conflict-free). Epilogue: out += acc.
// ---------------------------------------------------------------------------
__global__ __launch_bounds__(512) void aggregateB(const int2* __restrict__ pairs,
                                                  const int* __restrict__ cnt,
                                                  const float* __restrict__ y,
                                                  float* __restrict__ out, int N) {
    __shared__ float acc[BN * HID];  // 32 KB
    const int tid = threadIdx.x;
    const int lane = tid & 63;
    const int wv = tid >> 6;  // 0..7
    const int b = blockIdx.x;

    for (int i = tid; i < BN * HID; i += 512) acc[i] = 0.f;
    __syncthreads();

    const int m = cnt[b];
    const int per = (m + 7) >> 3;
    const int s = wv * per;
    const int t = min(s + per, m);
    const int2* pb = pairs + (size_t)b * CAP;

    int k = s;
    for (; k + 4 <= t; k += 4) {
        const int2 p0 = pb[k], p1 = pb[k + 1], p2 = pb[k + 2], p3 = pb[k + 3];
        const float v0 = y[(size_t)(p0.x & 0x1FFFF) * HID + lane];
        const float v1 = y[(size_t)(p1.x & 0x1FFFF) * HID + lane];
        const float v2 = y[(size_t)(p2.x & 0x1FFFF) * HID + lane];
        const float v3 = y[(size_t)(p3.x & 0x1FFFF) * HID + lane];
        atomicAdd(&acc[(p0.x >> 17) * HID + lane], __int_as_float(p0.y) * v0);
        atomicAdd(&acc[(p1.x >> 17) * HID + lane], __int_as_float(p1.y) * v1);
        atomicAdd(&acc[(p2.x >> 17) * HID + lane], __int_as_float(p2.y) * v2);
        atomicAdd(&acc[(p3.x >> 17) * HID + lane], __int_as_float(p3.y) * v3);
    }
    for (; k < t; ++k) {
        const int2 p = pb[k];
        const float v = y[(size_t)(p.x & 0x1FFFF) * HID + lane];
        atomicAdd(&acc[(p.x >> 17) * HID + lane], __int_as_float(p.y) * v);
    }
    __syncthreads();

    const size_t gb = (size_t)b * BN * HID;
    const int lim = min(BN * HID, (N - b * BN) * HID);
    for (int i = tid; i < lim; i += 512) out[gb + i] += acc[i];
}

// Fallback (R1 path): 16 thr/edge atomic scatter.
__global__ __launch_bounds__(256) void k2_atomic(const int* __restrict__ ei,
                                                 const float* __restrict__ ew,
                                                 const float* __restrict__ y,
                                                 float* __restrict__ out, int E) {
    const long t = (long)blockIdx.x * 256 + threadIdx.x;
    const long e = t >> 4;
    const int r = (int)(t & 15);
    if (e >= E) return;
    const int src = ei[e];
    const int dst = ei[(long)E + e];
    const float w = ew[e];
    const float4 v = ((const float4*)y)[(size_t)src * 16 + r];
    float* o = out + (size_t)dst * HID + r * 4;
    unsafeAtomicAdd(o + 0, w * v.x);
    unsafeAtomicAdd(o + 1, w * v.y);
    unsafeAtomicAdd(o + 2, w * v.z);
    unsafeAtomicAdd(o + 3, w * v.w);
}

extern "C" void kernel_launch(void* const* d_in, const int* in_sizes, int n_in,
                              void* d_out, int out_size, void* d_ws, size_t ws_size,
                              hipStream_t stream) {
    const float* x      = (const float*)d_in[0];
    const int*   ei     = (const int*)d_in[1];
    const float* ew     = (const float*)d_in[2];
    const float* W_rel  = (const float*)d_in[3];
    const float* b_rel  = (const float*)d_in[4];
    const float* W_root = (const float*)d_in[5];
    float* out = (float*)d_out;

    const int N = in_sizes[0] / IN_CH;  // 100000
    const int E = in_sizes[2];          // 3200000

    // ws layout: y | pairs | cnt | Wt
    char* base = (char*)d_ws;
    const size_t oY     = 0;
    const size_t oPairs = align16((size_t)N * HID * 4);
    const size_t oCnt   = oPairs + align16((size_t)NB * CAP * 8);
    const size_t oWt    = oCnt + align16((size_t)NB * 4);
    const size_t need   = oWt + (size_t)IN_CH * 128 * 4;

    float* y = (float*)(base + oY);

    // packing requires src < 2^17 and the fixed bucket geometry
    const bool fits = (ws_size >= need) && (N <= 100096) && (N <= (1 << 17)) &&
                      ((size_t)NB * BN >= (size_t)N);

    if (fits) {
        int2* pairs = (int2*)(base + oPairs);
        int*  cnt   = (int*)(base + oCnt);
        float* Wt   = (float*)(base + oWt);

        prep_wt<<<1, 128, 0, stream>>>(W_rel, W_root, Wt);
        k1<<<(N + 63) / 64, 256, 0, stream>>>(x, Wt, b_rel, y, out, N);
        hipMemsetAsync(cnt, 0, (size_t)NB * 4, stream);
        scatterB<<<(E + EPB - 1) / EPB, 256, 0, stream>>>(ei, ew, cnt, pairs, E);
        aggregateB<<<NB, 512, 0, stream>>>(pairs, cnt, y, out, N);
    } else {
        float* Wt = (float*)(base + align16((size_t)N * HID * 4));
        prep_wt<<<1, 128, 0, stream>>>(W_rel, W_root, Wt);
        k1<<<(N + 63) / 64, 256, 0, stream>>>(x, Wt, b_rel, y, out, N);
        const long thr2 = (long)E * 16;
        k2_atomic<<<(int)((thr2 + 255) / 256), 256, 0, stream>>>(ei, ew, y, out, E);
    }
}